// Round 7
// baseline (716.727 us; speedup 1.0000x reference)
//
#include <hip/hip_runtime.h>
#include <hip/hip_bf16.h>
#include <math.h>

// B=2, T=32, H=32, W=32, HID=64, IN=384, OUT=384, L=1024, rows=65536
// h5 layout: [b][c][t][l] -> b*2097152 + c*32768 + t*1024 + l
// OUTPUT IS FLOAT32 (reference returns fp32).
// ws layout (float offsets): gf[128] @0, bnp[256] @128, stat[256] @384,
// h5 @1024, a1 @4195328, a2 @8389632, x3(bf16) @12583936. total = 58.7 MB
// R12: k1 = x-from-global GEMM. The k1 wall, measured:
//  - both operands via LDS: LDS-pipe-bound, 128us best (R4, VALU 34%).
//  - big tile under cap: spill (R1,R5: 2+GB scratch); no cap: VGPR=256,
//    1-2 waves/SIMD, 201us (R3).
//  - scalar-W: compiler does NOT scalarize uniform W loads (R6: VALU 70%
//    at 7.6x FMA issue count, 223us).
//  R12: x fragments are single-use -> load DIRECT from global (L1 bcast,
//  imm offsets off 8 row-base pointers); only W (reused 8x) stays in LDS
//  (8KB/step dbuf, 1 barrier/step). Per wave-kq: VALU 64cyc(/SIMD),
//  LDS 48, VMEM-issue 32 -> VALU-bound. ~100 VGPR under (256,2).
// k2c fused BN stats (atomicAdd, zeroed in k0); k2d = 1-block finalize.

#define OFF_GF 0
#define OFF_BN 128
#define OFF_ST 384
#define OFF_H5 1024
#define OFF_A1 4195328
#define OFF_A2 8389632
#define OFF_X3 12583936

__device__ __forceinline__ float gelu_f(float v) {
    return 0.5f * v * (1.0f + erff(v * 0.70710678118654752f));
}

// ---------------------------------------------------------------------------
// K0: g = ifft_T(fw), F = ifft_T(fb) (T=32). gf: gr[32] gi[32] Fr[32] Fi[32]
// Also zeroes the BN-stat accumulators (re-zeroed on every graph replay).
// ---------------------------------------------------------------------------
__global__ __launch_bounds__(64) void k0_prep(const float* __restrict__ fw,
                                              const float* __restrict__ fb,
                                              float* __restrict__ gf,
                                              float* __restrict__ stat) {
    int tid = threadIdx.x;
    stat[tid] = 0.f;
    stat[64 + tid] = 0.f;
    stat[128 + tid] = 0.f;
    stat[192 + tid] = 0.f;
    if (tid < 32) {
        float gr = 0.f, gi = 0.f, Fr = 0.f, Fi = 0.f;
        for (int f = 0; f < 32; f++) {
            int ph = (f * tid) & 31;
            float ang = 6.283185307179586f * (float)ph * (1.0f / 32.0f);
            float s, c;
            __sincosf(ang, &s, &c);
            float wv = fw[f], bv = fb[f];
            gr += wv * c; gi += wv * s;
            Fr += bv * c; Fi += bv * s;
        }
        const float inv = 1.0f / 32.0f;
        gf[tid]      = gr * inv;
        gf[32 + tid] = gi * inv;
        gf[64 + tid] = Fr * inv;
        gf[96 + tid] = Fi * inv;
    }
}

// ---------------------------------------------------------------------------
// K1: down GEMM + bias + GELU -> h5 (channel-planar), x-from-global design.
// 512 blocks x 256 thr. Block: 128 rows x 64 ch, K=384 in 12 steps of 32.
// Thread: 8 rows x 4 ch. x: direct global float4 loads, imm offsets off 8
// row-base pointers (each 16B fragment hit by one wave-inst, 16-lane
// broadcast; L1/L2 stream). W: LDS double-buffer (64x36 per buf, 8KB),
// reused 8x per ds_read_b128; staged 2 steps ahead; ONE barrier per step.
// Epilogue: gelu+bias -> 4-phase LDS transpose (32 rows) -> planar float4.
// ---------------------------------------------------------------------------
__global__ __launch_bounds__(256, 2) void k1_down(const float* __restrict__ x,
                                                  const float* __restrict__ dw,
                                                  const float* __restrict__ db,
                                                  float* __restrict__ h5) {
    __shared__ __align__(16) float wsm[2 * 2304];   // W dbuf: [64 ch][36]
    __shared__ __align__(16) float st[64 * 36];     // epilogue transpose
    const int tid = threadIdx.x;
    const int row0 = blockIdx.x * 128;
    const int cg = tid & 15;   // ch  = cg + 16*i, i<4
    const int rg = tid >> 4;   // row = rg + 16*j, j<8  (rg 0..15)

    // 8 per-thread x row bases; all K offsets fit 13-bit imm ((kc+kq*4)*4 <= 1520)
    const float* xb0 = x + (row0 + rg) * 384;
    const float* xb1 = xb0 + 16 * 384;
    const float* xb2 = xb0 + 32 * 384;
    const float* xb3 = xb0 + 48 * 384;
    const float* xb4 = xb0 + 64 * 384;
    const float* xb5 = xb0 + 80 * 384;
    const float* xb6 = xb0 + 96 * 384;
    const float* xb7 = xb0 + 112 * 384;

    // W staging coords: c = tid>>2 (0..63), k8 = (tid&3)*8 (two float4)
    const int sc = tid >> 2;
    const int sk8 = (tid & 3) * 8;
    const float* wp = dw + sc * 384 + sk8;

    float acc[8][4];
#pragma unroll
    for (int j = 0; j < 8; j++)
#pragma unroll
        for (int i = 0; i < 4; i++) acc[j][i] = 0.f;

    // prologue: W tile 0 -> buf0, issue tile 1 loads
    float4 w0 = *(const float4*)(wp);
    float4 w1 = *(const float4*)(wp + 4);
    *(float4*)(wsm + sc * 36 + sk8) = w0;
    *(float4*)(wsm + sc * 36 + sk8 + 4) = w1;
    w0 = *(const float4*)(wp + 32);
    w1 = *(const float4*)(wp + 36);
    __syncthreads();

    for (int s = 0; s < 12; s++) {
        float* cb = wsm + (s & 1) * 2304;         // compute buffer
        float* nb = wsm + ((s + 1) & 1) * 2304;   // next buffer
        if (s < 11) {
            // tile s+1 regs -> nb (vmcnt wait lands here); nb's readers
            // (tile s-1 compute) finished before the last barrier.
            *(float4*)(nb + sc * 36 + sk8) = w0;
            *(float4*)(nb + sc * 36 + sk8 + 4) = w1;
            if (s < 10) {
                w0 = *(const float4*)(wp + (s + 2) * 32);
                w1 = *(const float4*)(wp + (s + 2) * 32 + 4);
            }
        }
        const int kc = s * 32;
#pragma unroll
        for (int kq = 0; kq < 8; kq++) {
            float4 wv[4];
#pragma unroll
            for (int i = 0; i < 4; i++)   // 16 addrs/wave, 2-way alias (free)
                wv[i] = *(const float4*)(cb + (cg + 16 * i) * 36 + kq * 4);
            const int ko = kc + kq * 4;
            float4 xv0 = *(const float4*)(xb0 + ko);
            float4 xv1 = *(const float4*)(xb1 + ko);
            float4 xv2 = *(const float4*)(xb2 + ko);
            float4 xv3 = *(const float4*)(xb3 + ko);
            float4 xv4 = *(const float4*)(xb4 + ko);
            float4 xv5 = *(const float4*)(xb5 + ko);
            float4 xv6 = *(const float4*)(xb6 + ko);
            float4 xv7 = *(const float4*)(xb7 + ko);
#pragma unroll
            for (int i = 0; i < 4; i++) {
                acc[0][i] += xv0.x * wv[i].x + xv0.y * wv[i].y + xv0.z * wv[i].z + xv0.w * wv[i].w;
                acc[1][i] += xv1.x * wv[i].x + xv1.y * wv[i].y + xv1.z * wv[i].z + xv1.w * wv[i].w;
                acc[2][i] += xv2.x * wv[i].x + xv2.y * wv[i].y + xv2.z * wv[i].z + xv2.w * wv[i].w;
                acc[3][i] += xv3.x * wv[i].x + xv3.y * wv[i].y + xv3.z * wv[i].z + xv3.w * wv[i].w;
                acc[4][i] += xv4.x * wv[i].x + xv4.y * wv[i].y + xv4.z * wv[i].z + xv4.w * wv[i].w;
                acc[5][i] += xv5.x * wv[i].x + xv5.y * wv[i].y + xv5.z * wv[i].z + xv5.w * wv[i].w;
                acc[6][i] += xv6.x * wv[i].x + xv6.y * wv[i].y + xv6.z * wv[i].z + xv6.w * wv[i].w;
                acc[7][i] += xv7.x * wv[i].x + xv7.y * wv[i].y + xv7.z * wv[i].z + xv7.w * wv[i].w;
            }
        }
        __syncthreads();
    }

    // epilogue: 4 phases of 32 rows: gelu(acc+bias) -> st[c][lr] -> planar
    const int b = row0 >> 15;
    const int t = (row0 >> 10) & 31;
    const int l0 = row0 & 1023;
    float bz[4];
#pragma unroll
    for (int i = 0; i < 4; i++) bz[i] = db[cg + 16 * i];
    const int rr4 = (tid & 7) * 4;   // 0..28
    const int cc0 = tid >> 3;        // 0..31
#pragma unroll
    for (int p = 0; p < 4; p++) {
        __syncthreads();
#pragma unroll
        for (int jj = 0; jj < 2; jj++) {
            const int lr = rg + 16 * jj;   // local row 0..31
#pragma unroll
            for (int i = 0; i < 4; i++)
                st[(cg + 16 * i) * 36 + lr] = gelu_f(acc[2 * p + jj][i] + bz[i]);
        }
        __syncthreads();
#pragma unroll
        for (int pass = 0; pass < 2; pass++) {
            const int c = cc0 + 32 * pass;
            float4 v = *(const float4*)(st + c * 36 + rr4);
            *(float4*)(h5 + b * 2097152 + c * 32768 + t * 1024 + l0 + 32 * p + rr4) = v;
        }
    }
}

// ---------------------------------------------------------------------------
// K2a: spatial depthwise (1,3,3) pad1 & (1,5,5) pad2 per (b,c,t) plane.
// 4096 blocks x 256 thr.
// ---------------------------------------------------------------------------
__global__ __launch_bounds__(256) void k2a_spatial(const float* __restrict__ h5,
                                                   const float* __restrict__ k31w,
                                                   const float* __restrict__ k31b,
                                                   const float* __restrict__ k51w,
                                                   const float* __restrict__ k51b,
                                                   float* __restrict__ a1,
                                                   float* __restrict__ a2) {
    __shared__ float pl[32 * 33];
    __shared__ float w3[9];
    __shared__ float w5[25];
    const int tid = threadIdx.x;
    const int bct = blockIdx.x;
    const int base = bct << 10;
    const int c = (bct >> 5) & 63;

#pragma unroll
    for (int i = 0; i < 4; i++) {
        int l = tid + i * 256;
        pl[(l >> 5) * 33 + (l & 31)] = h5[base + l];
    }
    if (tid < 9)  w3[tid] = k31w[c * 9 + tid];
    if (tid < 25) w5[tid] = k51w[c * 25 + tid];
    float b3 = k31b[c], b5 = k51b[c];
    __syncthreads();

#pragma unroll
    for (int i = 0; i < 4; i++) {
        int l = tid + i * 256;
        int h = l >> 5, w = l & 31;
        float s3 = b3;
#pragma unroll
        for (int dh = -1; dh <= 1; dh++) {
            int hh = h + dh;
            if (hh < 0 || hh > 31) continue;
#pragma unroll
            for (int dwi = -1; dwi <= 1; dwi++) {
                int ww = w + dwi;
                if (ww < 0 || ww > 31) continue;
                s3 += pl[hh * 33 + ww] * w3[(dh + 1) * 3 + dwi + 1];
            }
        }
        float s5 = b5;
#pragma unroll
        for (int dh = -2; dh <= 2; dh++) {
            int hh = h + dh;
            if (hh < 0 || hh > 31) continue;
#pragma unroll
            for (int dwi = -2; dwi <= 2; dwi++) {
                int ww = w + dwi;
                if (ww < 0 || ww > 31) continue;
                s5 += pl[hh * 33 + ww] * w5[(dh + 2) * 5 + dwi + 2];
            }
        }
        a1[base + l] = s3;
        a2[base + l] = s5;
    }
}

// ---------------------------------------------------------------------------
// K2b: FFT branch = complex circular conv along T (+ ifft(fb) delta at l==0),
// magnitude -> x3 (bf16). 512 blocks x 256 thr.
// ---------------------------------------------------------------------------
__global__ __launch_bounds__(256) void k2b_fft(const float* __restrict__ h5,
                                               __hip_bfloat16* __restrict__ x3,
                                               const float* __restrict__ gf) {
    __shared__ float col[32 * 256];
    __shared__ float gfs[128];
    const int tid = threadIdx.x;
    const int bid = blockIdx.x;
    const int bc = bid >> 2;
    const int l = (bid & 3) * 256 + tid;
    const int base = bc * 32768 + l;

    if (tid < 128) gfs[tid] = gf[tid];
#pragma unroll
    for (int t = 0; t < 32; t++) col[t * 256 + tid] = h5[base + t * 1024];
    __syncthreads();

    const bool dc = (l == 0);
    for (int t = 0; t < 32; t++) {
        float ar = dc ? gfs[64 + t] : 0.f;
        float ai = dc ? gfs[96 + t] : 0.f;
#pragma unroll
        for (int d = 0; d < 32; d++) {
            float xv = col[(((t - d) & 31) << 8) + tid];
            ar += xv * gfs[d];
            ai += xv * gfs[32 + d];
        }
        x3[base + t * 1024] = __float2bfloat16(sqrtf(ar * ar + ai * ai));
    }
}

// ---------------------------------------------------------------------------
// K2c: temporal depthwise convs (3,1,1) pad1 / (5,1,1) pad2, in-place a1/a2,
// FUSED with BN stat accumulation (sum, sumsq per channel -> atomicAdd).
// 512 blocks x 256 thr; one T-column per thread; each block = single channel.
// ---------------------------------------------------------------------------
__global__ __launch_bounds__(256) void k2c_temporal(float* __restrict__ a1,
                                                    float* __restrict__ a2,
                                                    const float* __restrict__ k32w,
                                                    const float* __restrict__ k32b,
                                                    const float* __restrict__ k52w,
                                                    const float* __restrict__ k52b,
                                                    float* __restrict__ stat) {
    __shared__ float r0[256], r1[256], r2[256], r3[256];
    const int tid = threadIdx.x;
    const int cid = blockIdx.x * 256 + tid;
    const int bc = cid >> 10;
    const int l = cid & 1023;
    const int c = bc & 63;
    const int base = bc * 32768 + l;

    float s1 = 0.f, q1 = 0.f, s2 = 0.f, q2 = 0.f;
    float a[32];
#pragma unroll
    for (int t = 0; t < 32; t++) a[t] = a1[base + t * 1024];
    {
        float w0 = k32w[c * 3], w1 = k32w[c * 3 + 1], w2 = k32w[c * 3 + 2];
        float bb = k32b[c];
#pragma unroll
        for (int t = 0; t < 32; t++) {
            float v = bb + a[t] * w1;
            if (t > 0)  v += a[t - 1] * w0;
            if (t < 31) v += a[t + 1] * w2;
            a1[base + t * 1024] = v;
            s1 += v; q1 += v * v;
        }
    }
#pragma unroll
    for (int t = 0; t < 32; t++) a[t] = a2[base + t * 1024];
    {
        float u0 = k52w[c * 5], u1 = k52w[c * 5 + 1], u2 = k52w[c * 5 + 2];
        float u3 = k52w[c * 5 + 3], u4 = k52w[c * 5 + 4];
        float bb = k52b[c];
#pragma unroll
        for (int t = 0; t < 32; t++) {
            float v = bb + a[t] * u2;
            if (t > 1)  v += a[t - 2] * u0;
            if (t > 0)  v += a[t - 1] * u1;
            if (t < 31) v += a[t + 1] * u3;
            if (t < 30) v += a[t + 2] * u4;
            a2[base + t * 1024] = v;
            s2 += v; q2 += v * v;
        }
    }
    // block reduce (all threads share channel c) + 4 atomics per block
    r0[tid] = s1; r1[tid] = q1; r2[tid] = s2; r3[tid] = q2;
    __syncthreads();
    for (int s = 128; s > 0; s >>= 1) {
        if (tid < s) {
            r0[tid] += r0[tid + s];
            r1[tid] += r1[tid + s];
            r2[tid] += r2[tid + s];
            r3[tid] += r3[tid + s];
        }
        __syncthreads();
    }
    if (tid == 0) {
        atomicAdd(&stat[c],       r0[0]);
        atomicAdd(&stat[64 + c],  r1[0]);
        atomicAdd(&stat[128 + c], r2[0]);
        atomicAdd(&stat[192 + c], r3[0]);
    }
}

// ---------------------------------------------------------------------------
// K2d: BN finalize from accumulated stats. 1 block x 64 thr.
// ---------------------------------------------------------------------------
__global__ __launch_bounds__(64) void k2d_bn(const float* __restrict__ stat,
                                             const float* __restrict__ g3,
                                             const float* __restrict__ b3,
                                             const float* __restrict__ g5,
                                             const float* __restrict__ b5,
                                             float* __restrict__ bnp) {
    const int c = threadIdx.x;
    const float inv_n = 1.0f / 65536.0f;
    float m1 = stat[c] * inv_n;
    float v1 = stat[64 + c] * inv_n - m1 * m1;
    float sc1 = g3[c] * rsqrtf(v1 + 1e-5f);
    float m2 = stat[128 + c] * inv_n;
    float v2 = stat[192 + c] * inv_n - m2 * m2;
    float sc2 = g5[c] * rsqrtf(v2 + 1e-5f);
    bnp[c] = sc1;
    bnp[64 + c] = b3[c] - m1 * sc1;
    bnp[128 + c] = sc2;
    bnp[192 + c] = b5[c] - m2 * sc2;
}

// ---------------------------------------------------------------------------
// K4: s = relu(bn(a1)) + relu(bn(a2)) + x3; attn = cw@s + cb; h5 += attn.
// 512 blocks x 256 thr; 128 positions x 64 ch per block.
// ---------------------------------------------------------------------------
__global__ __launch_bounds__(256) void k4_pointwise(float* __restrict__ h5,
                                                    const float* __restrict__ a1,
                                                    const float* __restrict__ a2,
                                                    const __hip_bfloat16* __restrict__ x3,
                                                    const float* __restrict__ cw,
                                                    const float* __restrict__ cb,
                                                    const float* __restrict__ bnp) {
    __shared__ float ls[64 * 129];
    __shared__ float cs[64 * 64];
    __shared__ float cbs[64];
    __shared__ float bns[256];
    const int tid = threadIdx.x;
    const int pos0 = blockIdx.x * 128;
    const int b = pos0 >> 15;
    const int rem = pos0 & 32767;
    const int t = rem >> 10;
    const int l0 = rem & 1023;
    const int pbase = b * 2097152 + t * 1024 + l0;

#pragma unroll
    for (int i = 0; i < 16; i++) cs[tid + i * 256] = cw[tid + i * 256];
    if (tid < 64) cbs[tid] = cb[tid];
    bns[tid] = bnp[tid];
    __syncthreads();

#pragma unroll
    for (int i = 0; i < 32; i++) {
        int q = tid + i * 256;
        int c = q >> 7, l = q & 127;
        int idx = pbase + c * 32768 + l;
        float v1 = fmaxf(bns[c] * a1[idx] + bns[64 + c], 0.f);
        float v2 = fmaxf(bns[128 + c] * a2[idx] + bns[192 + c], 0.f);
        ls[c * 129 + l] = v1 + v2 + __bfloat162float(x3[idx]);
    }
    __syncthreads();

    const int lidx = tid & 127;
    const int og = tid >> 7;
    float sreg[64];
#pragma unroll
    for (int c = 0; c < 64; c++) sreg[c] = ls[c * 129 + lidx];
    float acc[32];
#pragma unroll
    for (int oi = 0; oi < 32; oi++) acc[oi] = cbs[og * 32 + oi];
#pragma unroll
    for (int cq = 0; cq < 16; cq++) {
        float s0 = sreg[cq * 4], s1 = sreg[cq * 4 + 1];
        float s2 = sreg[cq * 4 + 2], s3 = sreg[cq * 4 + 3];
#pragma unroll
        for (int oi = 0; oi < 32; oi++) {
            float4 wv = *(const float4*)(cs + (og * 32 + oi) * 64 + cq * 4);
            acc[oi] += wv.x * s0 + wv.y * s1 + wv.z * s2 + wv.w * s3;
        }
    }
#pragma unroll
    for (int oi = 0; oi < 32; oi++) {
        int o = og * 32 + oi;
        int idx = pbase + o * 32768 + lidx;
        h5[idx] = h5[idx] + acc[oi];
    }
}

// ---------------------------------------------------------------------------
// K5: up GEMM + bias + GELU + residual -> FLOAT32 out.
// grid (3, 1024) x 256 thr; 64 rows x 128 cols per block; 8 rows x 4 cols
// per thread.
// ---------------------------------------------------------------------------
__global__ __launch_bounds__(256) void k5_up(const float* __restrict__ y5,
                                             const float* __restrict__ uw,
                                             const float* __restrict__ ub,
                                             const float* __restrict__ x,
                                             float* __restrict__ out) {
    __shared__ float ys_t[64 * 68];   // [row][k]
    __shared__ float wts[128 * 68];   // [c][k]
    const int tid = threadIdx.x;
    const int row0 = blockIdx.y * 64;
    const int c0 = blockIdx.x * 128;
    const int b = row0 >> 15;
    const int t = (row0 >> 10) & 31;
    const int l0 = row0 & 1023;
    const int ybase = b * 2097152 + t * 1024 + l0;

    // stage ys_t: 64 k x 64 r, global coalesced along r, LDS write stride 68
#pragma unroll
    for (int i = 0; i < 16; i++) {
        int e = tid + i * 256;
        int k = e >> 6, r = e & 63;
        ys_t[r * 68 + k] = y5[ybase + k * 32768 + r];
    }
    // stage wts: 128 c x 64 k, float4 both sides
#pragma unroll
    for (int i = 0; i < 8; i++) {
        int e = tid + i * 256;
        int c = e >> 4, k4 = e & 15;
        float4 v = *(const float4*)(uw + (c0 + c) * 64 + k4 * 4);
        *(float4*)(wts + c * 68 + k4 * 4) = v;
    }
    __syncthreads();

    const int cg = tid & 31;   // col lane: c = c0 + cg + 32*ci
    const int rg = tid >> 5;   // 0..7:     row = row0 + rg + 8*j
    float acc[8][4];
#pragma unroll
    for (int j = 0; j < 8; j++)
#pragma unroll
        for (int ci = 0; ci < 4; ci++) acc[j][ci] = 0.f;

#pragma unroll 2
    for (int kq = 0; kq < 16; kq++) {
        const int ko = kq * 4;
        float4 w0 = *(const float4*)(wts + (cg)      * 68 + ko);
        float4 w1 = *(const float4*)(wts + (cg + 32) * 68 + ko);
        float4 w2 = *(const float4*)(wts + (cg + 64) * 68 + ko);
        float4 w3 = *(const float4*)(wts + (cg + 96) * 68 + ko);
#pragma unroll
        for (int j = 0; j < 8; j++) {
            float4 yv = *(const float4*)(ys_t + (rg + 8 * j) * 68 + ko);
            acc[j][0] += yv.x * w0.x + yv.y * w0.y + yv.z * w0.z + yv.w * w0.w;
            acc[j][1] += yv.x * w1.x + yv.y * w1.y + yv.z * w1.z + yv.w * w1.w;
            acc[j][2] += yv.x * w2.x + yv.y * w2.y + yv.z * w2.z + yv.w * w2.w;
            acc[j][3] += yv.x * w3.x + yv.y * w3.y + yv.z * w3.z + yv.w * w3.w;
        }
    }

#pragma unroll
    for (int ci = 0; ci < 4; ci++) {
        int c = c0 + cg + 32 * ci;
        float ubv = ub[c];
#pragma unroll
        for (int j = 0; j < 8; j++) {
            int row = row0 + rg + 8 * j;
            float v = gelu_f(acc[j][ci] + ubv);
            out[row * 384 + c] = x[row * 384 + c] + v;
        }
    }
}

// ---------------------------------------------------------------------------
extern "C" void kernel_launch(void* const* d_in, const int* in_sizes, int n_in,
                              void* d_out, int out_size, void* d_ws, size_t ws_size,
                              hipStream_t stream) {
    const float* x      = (const float*)d_in[0];
    const float* down_w = (const float*)d_in[1];
    const float* down_b = (const float*)d_in[2];
    const float* k31w   = (const float*)d_in[3];
    const float* k31b   = (const float*)d_in[4];
    const float* k32w   = (const float*)d_in[5];
    const float* k32b   = (const float*)d_in[6];
    const float* bn3g   = (const float*)d_in[7];
    const float* bn3b   = (const float*)d_in[8];
    const float* k51w   = (const float*)d_in[9];
    const float* k51b   = (const float*)d_in[10];
    const float* k52w   = (const float*)d_in[11];
    const float* k52b   = (const float*)d_in[12];
    const float* bn5g   = (const float*)d_in[13];
    const float* bn5b   = (const float*)d_in[14];
    const float* conv_w = (const float*)d_in[15];
    const float* conv_b = (const float*)d_in[16];
    const float* fw     = (const float*)d_in[17];
    const float* fb     = (const float*)d_in[18];
    const float* up_w   = (const float*)d_in[19];
    const float* up_b   = (const float*)d_in[20];
    float* out = (float*)d_out;

    float* wsf = (float*)d_ws;
    float* gfb  = wsf + OFF_GF;
    float* bnp  = wsf + OFF_BN;
    float* stat = wsf + OFF_ST;
    float* h5   = wsf + OFF_H5;
    float* a1   = wsf + OFF_A1;
    float* a2   = wsf + OFF_A2;
    __hip_bfloat16* x3 = (__hip_bfloat16*)(wsf + OFF_X3);

    k0_prep<<<1, 64, 0, stream>>>(fw, fb, gfb, stat);
    k1_down<<<512, 256, 0, stream>>>(x, down_w, down_b, h5);
    k2a_spatial<<<4096, 256, 0, stream>>>(h5, k31w, k31b, k51w, k51b, a1, a2);
    k2b_fft<<<512, 256, 0, stream>>>(h5, x3, gfb);
    k2c_temporal<<<512, 256, 0, stream>>>(a1, a2, k32w, k32b, k52w, k52b, stat);
    k2d_bn<<<1, 64, 0, stream>>>(stat, bn3g, bn3b, bn5g, bn5b, bnp);
    k4_pointwise<<<512, 256, 0, stream>>>(h5, a1, a2, x3, conv_w, conv_b, bnp);
    k5_up<<<dim3(3, 1024), 256, 0, stream>>>(h5, up_w, up_b, x, out);
}

// Round 8
// 598.464 us; speedup vs baseline: 1.1976x; 1.1976x over previous
//
#include <hip/hip_runtime.h>
#include <hip/hip_bf16.h>
#include <math.h>

// B=2, T=32, H=32, W=32, HID=64, IN=384, OUT=384, L=1024, rows=65536
// h5 layout: [b][c][t][l] -> b*2097152 + c*32768 + t*1024 + l
// OUTPUT IS FLOAT32 (reference returns fp32).
// ws layout (float offsets): gf[128] @0, bnp[256] @128, stat[256] @384,
// h5 @1024, a1 @4195328, a2 @8389632, x3(bf16) @12583936. total = 58.7 MB
// R14: CONSOLIDATION. k1 reverted to R4's proven 4x4 kernel (128us,
// traffic==ideal, VALU 33% LDS-issue-bound). The k1 fp32 ledger is closed:
//  - 4x4 both-ops-LDS: 128us (R4)  <- floor for fp32, KEEP
//  - bigger tiles: spill at any cap (R1/R5/R7) or occ collapse (R3)
//  - scalar-W: compiler won't scalarize (R6, 223us)
//  - x-from-global: spill (R7, 910MB traffic)
// Kept from R5+: k2c-fused BN stats (atomicAdd, zeroed in k0), 1-block k2d.
// Next levers (not this round): bf16/MFMA k1; k4+k5 fusion.

#define OFF_GF 0
#define OFF_BN 128
#define OFF_ST 384
#define OFF_H5 1024
#define OFF_A1 4195328
#define OFF_A2 8389632
#define OFF_X3 12583936

__device__ __forceinline__ float gelu_f(float v) {
    return 0.5f * v * (1.0f + erff(v * 0.70710678118654752f));
}

// ---------------------------------------------------------------------------
// K0: g = ifft_T(fw), F = ifft_T(fb) (T=32). gf: gr[32] gi[32] Fr[32] Fi[32]
// Also zeroes the BN-stat accumulators (re-zeroed on every graph replay).
// ---------------------------------------------------------------------------
__global__ __launch_bounds__(64) void k0_prep(const float* __restrict__ fw,
                                              const float* __restrict__ fb,
                                              float* __restrict__ gf,
                                              float* __restrict__ stat) {
    int tid = threadIdx.x;
    stat[tid] = 0.f;
    stat[64 + tid] = 0.f;
    stat[128 + tid] = 0.f;
    stat[192 + tid] = 0.f;
    if (tid < 32) {
        float gr = 0.f, gi = 0.f, Fr = 0.f, Fi = 0.f;
        for (int f = 0; f < 32; f++) {
            int ph = (f * tid) & 31;
            float ang = 6.283185307179586f * (float)ph * (1.0f / 32.0f);
            float s, c;
            __sincosf(ang, &s, &c);
            float wv = fw[f], bv = fb[f];
            gr += wv * c; gi += wv * s;
            Fr += bv * c; Fi += bv * s;
        }
        const float inv = 1.0f / 32.0f;
        gf[tid]      = gr * inv;
        gf[32 + tid] = gi * inv;
        gf[64 + tid] = Fr * inv;
        gf[96 + tid] = Fi * inv;
    }
}

// ---------------------------------------------------------------------------
// K1: down GEMM + bias + GELU -> h5 (channel-planar).  (R4's proven kernel)
// 1024 blocks x 256 thr. Block: 64 rows x 64 ch, K=384 in 12 steps of 32.
// Thread: 4 rows x 4 ch. Double-buffered LDS (one barrier per K-step):
//   iter s: write tile s+1 (regs) -> buf^1, issue loads tile s+2,
//           compute buf, barrier.
// Epilogue: gelu(acc+bias) -> LDS transpose -> float4 planar h5 stores.
// DO NOT grow the per-thread tile: every larger variant spills (R1/R5/R7).
// ---------------------------------------------------------------------------
__global__ __launch_bounds__(256, 2) void k1_down(const float* __restrict__ x,
                                                  const float* __restrict__ dw,
                                                  const float* __restrict__ db,
                                                  float* __restrict__ h5) {
    // buf b: xs at sm + b*4608, ws at sm + b*4608 + 2304  (stride 36/row)
    __shared__ __align__(16) float sm[9216];
    const int tid = threadIdx.x;
    const int row0 = blockIdx.x * 64;
    const int cg = tid & 15;   // ch  = cg + 16*i, i<4
    const int rg = tid >> 4;   // row = rg + 16*j, j<4  (rg 0..15)

    // staging coords: thread loads rows/chs sr and sr+32 at k-quad sk
    const int sr = tid >> 3;        // 0..31
    const int sk = (tid & 7) * 4;   // 0,4,...,28
    const float* xp = x + (row0 + sr) * 384 + sk;
    const float* wp = dw + sr * 384 + sk;

    float acc[4][4];
#pragma unroll
    for (int j = 0; j < 4; j++)
#pragma unroll
        for (int i = 0; i < 4; i++) acc[j][i] = 0.f;

    // prologue: tile 0 -> buf0, issue tile 1 loads
    float4 rx0 = *(const float4*)(xp);
    float4 rx1 = *(const float4*)(xp + 32 * 384);
    float4 rw0 = *(const float4*)(wp);
    float4 rw1 = *(const float4*)(wp + 32 * 384);
    *(float4*)(sm + (sr)      * 36 + sk) = rx0;
    *(float4*)(sm + (sr + 32) * 36 + sk) = rx1;
    *(float4*)(sm + 2304 + (sr)      * 36 + sk) = rw0;
    *(float4*)(sm + 2304 + (sr + 32) * 36 + sk) = rw1;
    rx0 = *(const float4*)(xp + 32);
    rx1 = *(const float4*)(xp + 32 + 32 * 384);
    rw0 = *(const float4*)(wp + 32);
    rw1 = *(const float4*)(wp + 32 + 32 * 384);
    __syncthreads();

    for (int s = 0; s < 12; s++) {
        float* cb = sm + (s & 1) * 4608;         // compute buffer
        float* nb = sm + ((s + 1) & 1) * 4608;   // next buffer
        if (s < 11) {
            // tile s+1 regs -> nb (vmcnt wait lands here); safe: everyone
            // finished computing from nb (tile s-1) before last barrier.
            *(float4*)(nb + (sr)      * 36 + sk) = rx0;
            *(float4*)(nb + (sr + 32) * 36 + sk) = rx1;
            *(float4*)(nb + 2304 + (sr)      * 36 + sk) = rw0;
            *(float4*)(nb + 2304 + (sr + 32) * 36 + sk) = rw1;
            if (s < 10) {
                const int kc = (s + 2) * 32;
                rx0 = *(const float4*)(xp + kc);
                rx1 = *(const float4*)(xp + kc + 32 * 384);
                rw0 = *(const float4*)(wp + kc);
                rw1 = *(const float4*)(wp + kc + 32 * 384);
            }
        }
#pragma unroll
        for (int kq = 0; kq < 8; kq++) {
            float4 wv[4], xv[4];
#pragma unroll
            for (int i = 0; i < 4; i++)   // 16 addrs, banks 2-way (free)
                wv[i] = *(const float4*)(cb + 2304 + (cg + 16 * i) * 36 + kq * 4);
#pragma unroll
            for (int j = 0; j < 4; j++)   // 4 addrs/wave, 16-lane broadcast
                xv[j] = *(const float4*)(cb + (rg + 16 * j) * 36 + kq * 4);
#pragma unroll
            for (int j = 0; j < 4; j++)
#pragma unroll
                for (int i = 0; i < 4; i++)
                    acc[j][i] += xv[j].x * wv[i].x + xv[j].y * wv[i].y +
                                 xv[j].z * wv[i].z + xv[j].w * wv[i].w;
        }
        __syncthreads();
    }

    // epilogue: gelu(acc+bias) -> st[c][r] (stride 68) -> planar float4 write
    const int b = row0 >> 15;
    const int t = (row0 >> 10) & 31;
    const int l0 = row0 & 1023;
    float bz[4];
#pragma unroll
    for (int i = 0; i < 4; i++) bz[i] = db[cg + 16 * i];
    float* st = sm;   // 64*68 = 4352 floats <= 9216
#pragma unroll
    for (int j = 0; j < 4; j++)
#pragma unroll
        for (int i = 0; i < 4; i++)
            st[(cg + 16 * i) * 68 + (rg + 16 * j)] = gelu_f(acc[j][i] + bz[i]);
    __syncthreads();
    const int r4 = (tid & 15) * 4;
    const int cr = tid >> 4;
#pragma unroll
    for (int pass = 0; pass < 4; pass++) {
        const int c = cr + 16 * pass;
        float4 v = *(const float4*)(st + c * 68 + r4);
        *(float4*)(h5 + b * 2097152 + c * 32768 + t * 1024 + l0 + r4) = v;
    }
}

// ---------------------------------------------------------------------------
// K2a: spatial depthwise (1,3,3) pad1 & (1,5,5) pad2 per (b,c,t) plane.
// 4096 blocks x 256 thr.
// ---------------------------------------------------------------------------
__global__ __launch_bounds__(256) void k2a_spatial(const float* __restrict__ h5,
                                                   const float* __restrict__ k31w,
                                                   const float* __restrict__ k31b,
                                                   const float* __restrict__ k51w,
                                                   const float* __restrict__ k51b,
                                                   float* __restrict__ a1,
                                                   float* __restrict__ a2) {
    __shared__ float pl[32 * 33];
    __shared__ float w3[9];
    __shared__ float w5[25];
    const int tid = threadIdx.x;
    const int bct = blockIdx.x;
    const int base = bct << 10;
    const int c = (bct >> 5) & 63;

#pragma unroll
    for (int i = 0; i < 4; i++) {
        int l = tid + i * 256;
        pl[(l >> 5) * 33 + (l & 31)] = h5[base + l];
    }
    if (tid < 9)  w3[tid] = k31w[c * 9 + tid];
    if (tid < 25) w5[tid] = k51w[c * 25 + tid];
    float b3 = k31b[c], b5 = k51b[c];
    __syncthreads();

#pragma unroll
    for (int i = 0; i < 4; i++) {
        int l = tid + i * 256;
        int h = l >> 5, w = l & 31;
        float s3 = b3;
#pragma unroll
        for (int dh = -1; dh <= 1; dh++) {
            int hh = h + dh;
            if (hh < 0 || hh > 31) continue;
#pragma unroll
            for (int dwi = -1; dwi <= 1; dwi++) {
                int ww = w + dwi;
                if (ww < 0 || ww > 31) continue;
                s3 += pl[hh * 33 + ww] * w3[(dh + 1) * 3 + dwi + 1];
            }
        }
        float s5 = b5;
#pragma unroll
        for (int dh = -2; dh <= 2; dh++) {
            int hh = h + dh;
            if (hh < 0 || hh > 31) continue;
#pragma unroll
            for (int dwi = -2; dwi <= 2; dwi++) {
                int ww = w + dwi;
                if (ww < 0 || ww > 31) continue;
                s5 += pl[hh * 33 + ww] * w5[(dh + 2) * 5 + dwi + 2];
            }
        }
        a1[base + l] = s3;
        a2[base + l] = s5;
    }
}

// ---------------------------------------------------------------------------
// K2b: FFT branch = complex circular conv along T (+ ifft(fb) delta at l==0),
// magnitude -> x3 (bf16). 512 blocks x 256 thr.
// ---------------------------------------------------------------------------
__global__ __launch_bounds__(256) void k2b_fft(const float* __restrict__ h5,
                                               __hip_bfloat16* __restrict__ x3,
                                               const float* __restrict__ gf) {
    __shared__ float col[32 * 256];
    __shared__ float gfs[128];
    const int tid = threadIdx.x;
    const int bid = blockIdx.x;
    const int bc = bid >> 2;
    const int l = (bid & 3) * 256 + tid;
    const int base = bc * 32768 + l;

    if (tid < 128) gfs[tid] = gf[tid];
#pragma unroll
    for (int t = 0; t < 32; t++) col[t * 256 + tid] = h5[base + t * 1024];
    __syncthreads();

    const bool dc = (l == 0);
    for (int t = 0; t < 32; t++) {
        float ar = dc ? gfs[64 + t] : 0.f;
        float ai = dc ? gfs[96 + t] : 0.f;
#pragma unroll
        for (int d = 0; d < 32; d++) {
            float xv = col[(((t - d) & 31) << 8) + tid];
            ar += xv * gfs[d];
            ai += xv * gfs[32 + d];
        }
        x3[base + t * 1024] = __float2bfloat16(sqrtf(ar * ar + ai * ai));
    }
}

// ---------------------------------------------------------------------------
// K2c: temporal depthwise convs (3,1,1) pad1 / (5,1,1) pad2, in-place a1/a2,
// FUSED with BN stat accumulation (sum, sumsq per channel -> atomicAdd).
// 512 blocks x 256 thr; one T-column per thread; each block = single channel.
// ---------------------------------------------------------------------------
__global__ __launch_bounds__(256) void k2c_temporal(float* __restrict__ a1,
                                                    float* __restrict__ a2,
                                                    const float* __restrict__ k32w,
                                                    const float* __restrict__ k32b,
                                                    const float* __restrict__ k52w,
                                                    const float* __restrict__ k52b,
                                                    float* __restrict__ stat) {
    __shared__ float r0[256], r1[256], r2[256], r3[256];
    const int tid = threadIdx.x;
    const int cid = blockIdx.x * 256 + tid;
    const int bc = cid >> 10;
    const int l = cid & 1023;
    const int c = bc & 63;
    const int base = bc * 32768 + l;

    float s1 = 0.f, q1 = 0.f, s2 = 0.f, q2 = 0.f;
    float a[32];
#pragma unroll
    for (int t = 0; t < 32; t++) a[t] = a1[base + t * 1024];
    {
        float w0 = k32w[c * 3], w1 = k32w[c * 3 + 1], w2 = k32w[c * 3 + 2];
        float bb = k32b[c];
#pragma unroll
        for (int t = 0; t < 32; t++) {
            float v = bb + a[t] * w1;
            if (t > 0)  v += a[t - 1] * w0;
            if (t < 31) v += a[t + 1] * w2;
            a1[base + t * 1024] = v;
            s1 += v; q1 += v * v;
        }
    }
#pragma unroll
    for (int t = 0; t < 32; t++) a[t] = a2[base + t * 1024];
    {
        float u0 = k52w[c * 5], u1 = k52w[c * 5 + 1], u2 = k52w[c * 5 + 2];
        float u3 = k52w[c * 5 + 3], u4 = k52w[c * 5 + 4];
        float bb = k52b[c];
#pragma unroll
        for (int t = 0; t < 32; t++) {
            float v = bb + a[t] * u2;
            if (t > 1)  v += a[t - 2] * u0;
            if (t > 0)  v += a[t - 1] * u1;
            if (t < 31) v += a[t + 1] * u3;
            if (t < 30) v += a[t + 2] * u4;
            a2[base + t * 1024] = v;
            s2 += v; q2 += v * v;
        }
    }
    // block reduce (all threads share channel c) + 4 atomics per block
    r0[tid] = s1; r1[tid] = q1; r2[tid] = s2; r3[tid] = q2;
    __syncthreads();
    for (int s = 128; s > 0; s >>= 1) {
        if (tid < s) {
            r0[tid] += r0[tid + s];
            r1[tid] += r1[tid + s];
            r2[tid] += r2[tid + s];
            r3[tid] += r3[tid + s];
        }
        __syncthreads();
    }
    if (tid == 0) {
        atomicAdd(&stat[c],       r0[0]);
        atomicAdd(&stat[64 + c],  r1[0]);
        atomicAdd(&stat[128 + c], r2[0]);
        atomicAdd(&stat[192 + c], r3[0]);
    }
}

// ---------------------------------------------------------------------------
// K2d: BN finalize from accumulated stats. 1 block x 64 thr.
// ---------------------------------------------------------------------------
__global__ __launch_bounds__(64) void k2d_bn(const float* __restrict__ stat,
                                             const float* __restrict__ g3,
                                             const float* __restrict__ b3,
                                             const float* __restrict__ g5,
                                             const float* __restrict__ b5,
                                             float* __restrict__ bnp) {
    const int c = threadIdx.x;
    const float inv_n = 1.0f / 65536.0f;
    float m1 = stat[c] * inv_n;
    float v1 = stat[64 + c] * inv_n - m1 * m1;
    float sc1 = g3[c] * rsqrtf(v1 + 1e-5f);
    float m2 = stat[128 + c] * inv_n;
    float v2 = stat[192 + c] * inv_n - m2 * m2;
    float sc2 = g5[c] * rsqrtf(v2 + 1e-5f);
    bnp[c] = sc1;
    bnp[64 + c] = b3[c] - m1 * sc1;
    bnp[128 + c] = sc2;
    bnp[192 + c] = b5[c] - m2 * sc2;
}

// ---------------------------------------------------------------------------
// K4: s = relu(bn(a1)) + relu(bn(a2)) + x3; attn = cw@s + cb; h5 += attn.
// 512 blocks x 256 thr; 128 positions x 64 ch per block.
// ---------------------------------------------------------------------------
__global__ __launch_bounds__(256) void k4_pointwise(float* __restrict__ h5,
                                                    const float* __restrict__ a1,
                                                    const float* __restrict__ a2,
                                                    const __hip_bfloat16* __restrict__ x3,
                                                    const float* __restrict__ cw,
                                                    const float* __restrict__ cb,
                                                    const float* __restrict__ bnp) {
    __shared__ float ls[64 * 129];
    __shared__ float cs[64 * 64];
    __shared__ float cbs[64];
    __shared__ float bns[256];
    const int tid = threadIdx.x;
    const int pos0 = blockIdx.x * 128;
    const int b = pos0 >> 15;
    const int rem = pos0 & 32767;
    const int t = rem >> 10;
    const int l0 = rem & 1023;
    const int pbase = b * 2097152 + t * 1024 + l0;

#pragma unroll
    for (int i = 0; i < 16; i++) cs[tid + i * 256] = cw[tid + i * 256];
    if (tid < 64) cbs[tid] = cb[tid];
    bns[tid] = bnp[tid];
    __syncthreads();

#pragma unroll
    for (int i = 0; i < 32; i++) {
        int q = tid + i * 256;
        int c = q >> 7, l = q & 127;
        int idx = pbase + c * 32768 + l;
        float v1 = fmaxf(bns[c] * a1[idx] + bns[64 + c], 0.f);
        float v2 = fmaxf(bns[128 + c] * a2[idx] + bns[192 + c], 0.f);
        ls[c * 129 + l] = v1 + v2 + __bfloat162float(x3[idx]);
    }
    __syncthreads();

    const int lidx = tid & 127;
    const int og = tid >> 7;
    float sreg[64];
#pragma unroll
    for (int c = 0; c < 64; c++) sreg[c] = ls[c * 129 + lidx];
    float acc[32];
#pragma unroll
    for (int oi = 0; oi < 32; oi++) acc[oi] = cbs[og * 32 + oi];
#pragma unroll
    for (int cq = 0; cq < 16; cq++) {
        float s0 = sreg[cq * 4], s1 = sreg[cq * 4 + 1];
        float s2 = sreg[cq * 4 + 2], s3 = sreg[cq * 4 + 3];
#pragma unroll
        for (int oi = 0; oi < 32; oi++) {
            float4 wv = *(const float4*)(cs + (og * 32 + oi) * 64 + cq * 4);
            acc[oi] += wv.x * s0 + wv.y * s1 + wv.z * s2 + wv.w * s3;
        }
    }
#pragma unroll
    for (int oi = 0; oi < 32; oi++) {
        int o = og * 32 + oi;
        int idx = pbase + o * 32768 + lidx;
        h5[idx] = h5[idx] + acc[oi];
    }
}

// ---------------------------------------------------------------------------
// K5: up GEMM + bias + GELU + residual -> FLOAT32 out.
// grid (3, 1024) x 256 thr; 64 rows x 128 cols per block; 8 rows x 4 cols
// per thread.
// ---------------------------------------------------------------------------
__global__ __launch_bounds__(256) void k5_up(const float* __restrict__ y5,
                                             const float* __restrict__ uw,
                                             const float* __restrict__ ub,
                                             const float* __restrict__ x,
                                             float* __restrict__ out) {
    __shared__ float ys_t[64 * 68];   // [row][k]
    __shared__ float wts[128 * 68];   // [c][k]
    const int tid = threadIdx.x;
    const int row0 = blockIdx.y * 64;
    const int c0 = blockIdx.x * 128;
    const int b = row0 >> 15;
    const int t = (row0 >> 10) & 31;
    const int l0 = row0 & 1023;
    const int ybase = b * 2097152 + t * 1024 + l0;

    // stage ys_t: 64 k x 64 r, global coalesced along r, LDS write stride 68
#pragma unroll
    for (int i = 0; i < 16; i++) {
        int e = tid + i * 256;
        int k = e >> 6, r = e & 63;
        ys_t[r * 68 + k] = y5[ybase + k * 32768 + r];
    }
    // stage wts: 128 c x 64 k, float4 both sides
#pragma unroll
    for (int i = 0; i < 8; i++) {
        int e = tid + i * 256;
        int c = e >> 4, k4 = e & 15;
        float4 v = *(const float4*)(uw + (c0 + c) * 64 + k4 * 4);
        *(float4*)(wts + c * 68 + k4 * 4) = v;
    }
    __syncthreads();

    const int cg = tid & 31;   // col lane: c = c0 + cg + 32*ci
    const int rg = tid >> 5;   // 0..7:     row = row0 + rg + 8*j
    float acc[8][4];
#pragma unroll
    for (int j = 0; j < 8; j++)
#pragma unroll
        for (int ci = 0; ci < 4; ci++) acc[j][ci] = 0.f;

#pragma unroll 2
    for (int kq = 0; kq < 16; kq++) {
        const int ko = kq * 4;
        float4 w0 = *(const float4*)(wts + (cg)      * 68 + ko);
        float4 w1 = *(const float4*)(wts + (cg + 32) * 68 + ko);
        float4 w2 = *(const float4*)(wts + (cg + 64) * 68 + ko);
        float4 w3 = *(const float4*)(wts + (cg + 96) * 68 + ko);
#pragma unroll
        for (int j = 0; j < 8; j++) {
            float4 yv = *(const float4*)(ys_t + (rg + 8 * j) * 68 + ko);
            acc[j][0] += yv.x * w0.x + yv.y * w0.y + yv.z * w0.z + yv.w * w0.w;
            acc[j][1] += yv.x * w1.x + yv.y * w1.y + yv.z * w1.z + yv.w * w1.w;
            acc[j][2] += yv.x * w2.x + yv.y * w2.y + yv.z * w2.z + yv.w * w2.w;
            acc[j][3] += yv.x * w3.x + yv.y * w3.y + yv.z * w3.z + yv.w * w3.w;
        }
    }

#pragma unroll
    for (int ci = 0; ci < 4; ci++) {
        int c = c0 + cg + 32 * ci;
        float ubv = ub[c];
#pragma unroll
        for (int j = 0; j < 8; j++) {
            int row = row0 + rg + 8 * j;
            float v = gelu_f(acc[j][ci] + ubv);
            out[row * 384 + c] = x[row * 384 + c] + v;
        }
    }
}

// ---------------------------------------------------------------------------
extern "C" void kernel_launch(void* const* d_in, const int* in_sizes, int n_in,
                              void* d_out, int out_size, void* d_ws, size_t ws_size,
                              hipStream_t stream) {
    const float* x      = (const float*)d_in[0];
    const float* down_w = (const float*)d_in[1];
    const float* down_b = (const float*)d_in[2];
    const float* k31w   = (const float*)d_in[3];
    const float* k31b   = (const float*)d_in[4];
    const float* k32w   = (const float*)d_in[5];
    const float* k32b   = (const float*)d_in[6];
    const float* bn3g   = (const float*)d_in[7];
    const float* bn3b   = (const float*)d_in[8];
    const float* k51w   = (const float*)d_in[9];
    const float* k51b   = (const float*)d_in[10];
    const float* k52w   = (const float*)d_in[11];
    const float* k52b   = (const float*)d_in[12];
    const float* bn5g   = (const float*)d_in[13];
    const float* bn5b   = (const float*)d_in[14];
    const float* conv_w = (const float*)d_in[15];
    const float* conv_b = (const float*)d_in[16];
    const float* fw     = (const float*)d_in[17];
    const float* fb     = (const float*)d_in[18];
    const float* up_w   = (const float*)d_in[19];
    const float* up_b   = (const float*)d_in[20];
    float* out = (float*)d_out;

    float* wsf = (float*)d_ws;
    float* gfb  = wsf + OFF_GF;
    float* bnp  = wsf + OFF_BN;
    float* stat = wsf + OFF_ST;
    float* h5   = wsf + OFF_H5;
    float* a1   = wsf + OFF_A1;
    float* a2   = wsf + OFF_A2;
    __hip_bfloat16* x3 = (__hip_bfloat16*)(wsf + OFF_X3);

    k0_prep<<<1, 64, 0, stream>>>(fw, fb, gfb, stat);
    k1_down<<<1024, 256, 0, stream>>>(x, down_w, down_b, h5);
    k2a_spatial<<<4096, 256, 0, stream>>>(h5, k31w, k31b, k51w, k51b, a1, a2);
    k2b_fft<<<512, 256, 0, stream>>>(h5, x3, gfb);
    k2c_temporal<<<512, 256, 0, stream>>>(a1, a2, k32w, k32b, k52w, k52b, stat);
    k2d_bn<<<1, 64, 0, stream>>>(stat, bn3g, bn3b, bn5g, bn5b, bnp);
    k4_pointwise<<<512, 256, 0, stream>>>(h5, a1, a2, x3, conv_w, conv_b, bnp);
    k5_up<<<dim3(3, 1024), 256, 0, stream>>>(h5, up_w, up_b, x, out);
}

// Round 9
// 379.614 us; speedup vs baseline: 1.8880x; 1.5765x over previous
//
#include <hip/hip_runtime.h>
#include <hip/hip_bf16.h>
#include <math.h>

// B=2, T=32, H=32, W=32, HID=64, IN=384, OUT=384, L=1024, rows=65536
// h5 layout: [b][c][t][l] -> b*2097152 + c*32768 + t*1024 + l
// OUTPUT IS FLOAT32 (reference returns fp32).
// ws layout (float offsets): gf[128] @0, bnp[256] @128, stat[256] @384,
// h5 @1024, a1 @4195328, a2 @8389632, x3(bf16) @12583936. total = 58.7 MB
// R15: k1 -> split-bf16 MFMA GEMM (x=x_hi+x_lo, w=w_hi+w_lo, 3 mfma per
// tile: hi*hi + lo*hi + hi*lo => fp32-comparable accuracy). fp32 ledger
// (R1-R8): 4x4-LDS = 128us floor (LDS-issue-bound); all bigger tiles spill;
// scalar-W not scalarized; x-from-global spills. MFMA work = 197K insts
// ~ 0.4us matrix-pipe: kernel becomes staging-bound (~16us HBM + cvt).
// mfma_f32_16x16x32_bf16 layout (guide, m89 HW-verified): A row=l&15,
// k=(l>>4)*8+i; B col=l&15; C/D col=l&15, row=(l>>4)*4+reg.
// Kept: k2c-fused BN stats (atomicAdd, zeroed in k0), 1-block k2d.

#define OFF_GF 0
#define OFF_BN 128
#define OFF_ST 384
#define OFF_H5 1024
#define OFF_A1 4195328
#define OFF_A2 8389632
#define OFF_X3 12583936

typedef __attribute__((ext_vector_type(8))) short short8v;   // 8 bf16
typedef __attribute__((ext_vector_type(4))) float float4v;   // mfma C/D

__device__ __forceinline__ float gelu_f(float v) {
    return 0.5f * v * (1.0f + erff(v * 0.70710678118654752f));
}

// split f into hi (bf16 RNE) and lo (bf16 RNE of residual)
#define CVT1(F, H, L) {                                              \
    unsigned u = __float_as_uint(F);                                 \
    unsigned rh = (u + 0x7FFFu + ((u >> 16) & 1u)) & 0xFFFF0000u;    \
    (H) = (short)(rh >> 16);                                         \
    float fl = (F) - __uint_as_float(rh);                            \
    unsigned ul = __float_as_uint(fl);                               \
    (L) = (short)((ul + 0x7FFFu + ((ul >> 16) & 1u)) >> 16);         \
}

// ---------------------------------------------------------------------------
// K0: g = ifft_T(fw), F = ifft_T(fb) (T=32). gf: gr[32] gi[32] Fr[32] Fi[32]
// Also zeroes the BN-stat accumulators (re-zeroed on every graph replay).
// ---------------------------------------------------------------------------
__global__ __launch_bounds__(64) void k0_prep(const float* __restrict__ fw,
                                              const float* __restrict__ fb,
                                              float* __restrict__ gf,
                                              float* __restrict__ stat) {
    int tid = threadIdx.x;
    stat[tid] = 0.f;
    stat[64 + tid] = 0.f;
    stat[128 + tid] = 0.f;
    stat[192 + tid] = 0.f;
    if (tid < 32) {
        float gr = 0.f, gi = 0.f, Fr = 0.f, Fi = 0.f;
        for (int f = 0; f < 32; f++) {
            int ph = (f * tid) & 31;
            float ang = 6.283185307179586f * (float)ph * (1.0f / 32.0f);
            float s, c;
            __sincosf(ang, &s, &c);
            float wv = fw[f], bv = fb[f];
            gr += wv * c; gi += wv * s;
            Fr += bv * c; Fi += bv * s;
        }
        const float inv = 1.0f / 32.0f;
        gf[tid]      = gr * inv;
        gf[32 + tid] = gi * inv;
        gf[64 + tid] = Fr * inv;
        gf[96 + tid] = Fi * inv;
    }
}

// ---------------------------------------------------------------------------
// K1: down GEMM + bias + GELU -> h5 (channel-planar), split-bf16 MFMA.
// 1024 blocks x 256 thr (4 waves). Block: 64 rows x 64 ch, K=384 in 12
// steps of 32. Wave w: rows [16w,16w+16) x 64 ch = 4 acc tiles (float4).
// Per step per wave: 2 A-frag + 8 B-frag ds_reads + 12 mfma.
// LDS: per buf 4 arrays [64][40] shorts (A_hi,A_lo,B_hi,B_lo), dbuf,
// stride 40 shorts = 80B (16B-aligned b128, 2-way banks). One barrier/step,
// staging regs preloaded 2 steps ahead (R4's proven schedule).
// Epilogue: gelu(acc+bias) -> st[c][r] (float, stride 68) -> planar float4.
// ---------------------------------------------------------------------------
__global__ __launch_bounds__(256, 2) void k1_down(const float* __restrict__ x,
                                                  const float* __restrict__ dw,
                                                  const float* __restrict__ db,
                                                  float* __restrict__ h5) {
    __shared__ __align__(16) short sm2[20480];   // 2 bufs x 4 arrays x 64*40
    const int tid = threadIdx.x;
    const int row0 = blockIdx.x * 64;
    const int wid = tid >> 6;
    const int lane = tid & 63;

    // staging coords: srow = row (A) / ch (B), skq = k-octet
    const int srow = tid >> 2;        // 0..63
    const int skq = (tid & 3) * 8;    // 0,8,16,24
    const float* xp = x + (row0 + srow) * 384 + skq;
    const float* wp = dw + srow * 384 + skq;
    const int wbase = srow * 40 + skq;

    // fragment read offsets (short indices)
    const int a_off = (16 * wid + (lane & 15)) * 40 + (lane >> 4) * 8;
    const int b_off = (lane & 15) * 40 + (lane >> 4) * 8;   // + 16*ct*40

    float4v acc[4];
#pragma unroll
    for (int i = 0; i < 4; i++) acc[i] = (float4v)(0.f);

    float4 xa, xb, wa, wb;
    short8v xhi, xlo, whi, wlo;

    // convert the 16 staged floats of (xa,xb,wa,wb) into hi/lo short8s
#define CVT_STAGE()                                                   \
    CVT1(xa.x, xhi[0], xlo[0]); CVT1(xa.y, xhi[1], xlo[1]);           \
    CVT1(xa.z, xhi[2], xlo[2]); CVT1(xa.w, xhi[3], xlo[3]);           \
    CVT1(xb.x, xhi[4], xlo[4]); CVT1(xb.y, xhi[5], xlo[5]);           \
    CVT1(xb.z, xhi[6], xlo[6]); CVT1(xb.w, xhi[7], xlo[7]);           \
    CVT1(wa.x, whi[0], wlo[0]); CVT1(wa.y, whi[1], wlo[1]);           \
    CVT1(wa.z, whi[2], wlo[2]); CVT1(wa.w, whi[3], wlo[3]);           \
    CVT1(wb.x, whi[4], wlo[4]); CVT1(wb.y, whi[5], wlo[5]);           \
    CVT1(wb.z, whi[6], wlo[6]); CVT1(wb.w, whi[7], wlo[7]);

#define STAGE_TO(buf)                                                 \
    *(short8v*)((buf) + wbase)        = xhi;                          \
    *(short8v*)((buf) + 2560 + wbase) = xlo;                          \
    *(short8v*)((buf) + 5120 + wbase) = whi;                          \
    *(short8v*)((buf) + 7680 + wbase) = wlo;

    // prologue: tile 0 -> buf0; preload tile 1
    xa = *(const float4*)(xp);     xb = *(const float4*)(xp + 4);
    wa = *(const float4*)(wp);     wb = *(const float4*)(wp + 4);
    CVT_STAGE();
    STAGE_TO(sm2);
    xa = *(const float4*)(xp + 32); xb = *(const float4*)(xp + 36);
    wa = *(const float4*)(wp + 32); wb = *(const float4*)(wp + 36);
    __syncthreads();

    for (int s = 0; s < 12; s++) {
        short* cb = sm2 + (s & 1) * 10240;
        short* nb = sm2 + ((s + 1) & 1) * 10240;
        if (s < 11) {
            CVT_STAGE();
            STAGE_TO(nb);
            if (s < 10) {
                const int kc = (s + 2) * 32;
                xa = *(const float4*)(xp + kc); xb = *(const float4*)(xp + kc + 4);
                wa = *(const float4*)(wp + kc); wb = *(const float4*)(wp + kc + 4);
            }
        }
        short8v ah = *(short8v*)(cb + a_off);
        short8v al = *(short8v*)(cb + 2560 + a_off);
#pragma unroll
        for (int ct = 0; ct < 4; ct++) {
            short8v bh = *(short8v*)(cb + 5120 + ct * 640 + b_off);
            short8v bl = *(short8v*)(cb + 7680 + ct * 640 + b_off);
            acc[ct] = __builtin_amdgcn_mfma_f32_16x16x32_bf16(ah, bh, acc[ct], 0, 0, 0);
            acc[ct] = __builtin_amdgcn_mfma_f32_16x16x32_bf16(al, bh, acc[ct], 0, 0, 0);
            acc[ct] = __builtin_amdgcn_mfma_f32_16x16x32_bf16(ah, bl, acc[ct], 0, 0, 0);
        }
        __syncthreads();
    }

    // epilogue: D lane layout col=lane&15 (ch), row=(lane>>4)*4+reg.
    // gelu(acc+bias) -> st[ch][row] (float, stride 68) -> planar float4.
    const int b = row0 >> 15;
    const int t = (row0 >> 10) & 31;
    const int l0 = row0 & 1023;
    float* st = (float*)sm2;   // 64*68*4 = 17408 B <= 40960 B
    float bz[4];
#pragma unroll
    for (int ct = 0; ct < 4; ct++) bz[ct] = db[ct * 16 + (lane & 15)];
#pragma unroll
    for (int ct = 0; ct < 4; ct++) {
        const int ch = ct * 16 + (lane & 15);
#pragma unroll
        for (int r = 0; r < 4; r++) {
            const int row = 16 * wid + (lane >> 4) * 4 + r;
            st[ch * 68 + row] = gelu_f(acc[ct][r] + bz[ct]);
        }
    }
    __syncthreads();
    const int r4 = (tid & 15) * 4;
    const int cr = tid >> 4;
#pragma unroll
    for (int pass = 0; pass < 4; pass++) {
        const int c = cr + 16 * pass;
        float4 v = *(const float4*)(st + c * 68 + r4);
        *(float4*)(h5 + b * 2097152 + c * 32768 + t * 1024 + l0 + r4) = v;
    }
}

// ---------------------------------------------------------------------------
// K2a: spatial depthwise (1,3,3) pad1 & (1,5,5) pad2 per (b,c,t) plane.
// 4096 blocks x 256 thr.
// ---------------------------------------------------------------------------
__global__ __launch_bounds__(256) void k2a_spatial(const float* __restrict__ h5,
                                                   const float* __restrict__ k31w,
                                                   const float* __restrict__ k31b,
                                                   const float* __restrict__ k51w,
                                                   const float* __restrict__ k51b,
                                                   float* __restrict__ a1,
                                                   float* __restrict__ a2) {
    __shared__ float pl[32 * 33];
    __shared__ float w3[9];
    __shared__ float w5[25];
    const int tid = threadIdx.x;
    const int bct = blockIdx.x;
    const int base = bct << 10;
    const int c = (bct >> 5) & 63;

#pragma unroll
    for (int i = 0; i < 4; i++) {
        int l = tid + i * 256;
        pl[(l >> 5) * 33 + (l & 31)] = h5[base + l];
    }
    if (tid < 9)  w3[tid] = k31w[c * 9 + tid];
    if (tid < 25) w5[tid] = k51w[c * 25 + tid];
    float b3 = k31b[c], b5 = k51b[c];
    __syncthreads();

#pragma unroll
    for (int i = 0; i < 4; i++) {
        int l = tid + i * 256;
        int h = l >> 5, w = l & 31;
        float s3 = b3;
#pragma unroll
        for (int dh = -1; dh <= 1; dh++) {
            int hh = h + dh;
            if (hh < 0 || hh > 31) continue;
#pragma unroll
            for (int dwi = -1; dwi <= 1; dwi++) {
                int ww = w + dwi;
                if (ww < 0 || ww > 31) continue;
                s3 += pl[hh * 33 + ww] * w3[(dh + 1) * 3 + dwi + 1];
            }
        }
        float s5 = b5;
#pragma unroll
        for (int dh = -2; dh <= 2; dh++) {
            int hh = h + dh;
            if (hh < 0 || hh > 31) continue;
#pragma unroll
            for (int dwi = -2; dwi <= 2; dwi++) {
                int ww = w + dwi;
                if (ww < 0 || ww > 31) continue;
                s5 += pl[hh * 33 + ww] * w5[(dh + 2) * 5 + dwi + 2];
            }
        }
        a1[base + l] = s3;
        a2[base + l] = s5;
    }
}

// ---------------------------------------------------------------------------
// K2b: FFT branch = complex circular conv along T (+ ifft(fb) delta at l==0),
// magnitude -> x3 (bf16). 512 blocks x 256 thr.
// ---------------------------------------------------------------------------
__global__ __launch_bounds__(256) void k2b_fft(const float* __restrict__ h5,
                                               __hip_bfloat16* __restrict__ x3,
                                               const float* __restrict__ gf) {
    __shared__ float col[32 * 256];
    __shared__ float gfs[128];
    const int tid = threadIdx.x;
    const int bid = blockIdx.x;
    const int bc = bid >> 2;
    const int l = (bid & 3) * 256 + tid;
    const int base = bc * 32768 + l;

    if (tid < 128) gfs[tid] = gf[tid];
#pragma unroll
    for (int t = 0; t < 32; t++) col[t * 256 + tid] = h5[base + t * 1024];
    __syncthreads();

    const bool dc = (l == 0);
    for (int t = 0; t < 32; t++) {
        float ar = dc ? gfs[64 + t] : 0.f;
        float ai = dc ? gfs[96 + t] : 0.f;
#pragma unroll
        for (int d = 0; d < 32; d++) {
            float xv = col[(((t - d) & 31) << 8) + tid];
            ar += xv * gfs[d];
            ai += xv * gfs[32 + d];
        }
        x3[base + t * 1024] = __float2bfloat16(sqrtf(ar * ar + ai * ai));
    }
}

// ---------------------------------------------------------------------------
// K2c: temporal depthwise convs (3,1,1) pad1 / (5,1,1) pad2, in-place a1/a2,
// FUSED with BN stat accumulation (sum, sumsq per channel -> atomicAdd).
// 512 blocks x 256 thr; one T-column per thread; each block = single channel.
// ---------------------------------------------------------------------------
__global__ __launch_bounds__(256) void k2c_temporal(float* __restrict__ a1,
                                                    float* __restrict__ a2,
                                                    const float* __restrict__ k32w,
                                                    const float* __restrict__ k32b,
                                                    const float* __restrict__ k52w,
                                                    const float* __restrict__ k52b,
                                                    float* __restrict__ stat) {
    __shared__ float r0[256], r1[256], r2[256], r3[256];
    const int tid = threadIdx.x;
    const int cid = blockIdx.x * 256 + tid;
    const int bc = cid >> 10;
    const int l = cid & 1023;
    const int c = bc & 63;
    const int base = bc * 32768 + l;

    float s1 = 0.f, q1 = 0.f, s2 = 0.f, q2 = 0.f;
    float a[32];
#pragma unroll
    for (int t = 0; t < 32; t++) a[t] = a1[base + t * 1024];
    {
        float w0 = k32w[c * 3], w1 = k32w[c * 3 + 1], w2 = k32w[c * 3 + 2];
        float bb = k32b[c];
#pragma unroll
        for (int t = 0; t < 32; t++) {
            float v = bb + a[t] * w1;
            if (t > 0)  v += a[t - 1] * w0;
            if (t < 31) v += a[t + 1] * w2;
            a1[base + t * 1024] = v;
            s1 += v; q1 += v * v;
        }
    }
#pragma unroll
    for (int t = 0; t < 32; t++) a[t] = a2[base + t * 1024];
    {
        float u0 = k52w[c * 5], u1 = k52w[c * 5 + 1], u2 = k52w[c * 5 + 2];
        float u3 = k52w[c * 5 + 3], u4 = k52w[c * 5 + 4];
        float bb = k52b[c];
#pragma unroll
        for (int t = 0; t < 32; t++) {
            float v = bb + a[t] * u2;
            if (t > 1)  v += a[t - 2] * u0;
            if (t > 0)  v += a[t - 1] * u1;
            if (t < 31) v += a[t + 1] * u3;
            if (t < 30) v += a[t + 2] * u4;
            a2[base + t * 1024] = v;
            s2 += v; q2 += v * v;
        }
    }
    // block reduce (all threads share channel c) + 4 atomics per block
    r0[tid] = s1; r1[tid] = q1; r2[tid] = s2; r3[tid] = q2;
    __syncthreads();
    for (int s = 128; s > 0; s >>= 1) {
        if (tid < s) {
            r0[tid] += r0[tid + s];
            r1[tid] += r1[tid + s];
            r2[tid] += r2[tid + s];
            r3[tid] += r3[tid + s];
        }
        __syncthreads();
    }
    if (tid == 0) {
        atomicAdd(&stat[c],       r0[0]);
        atomicAdd(&stat[64 + c],  r1[0]);
        atomicAdd(&stat[128 + c], r2[0]);
        atomicAdd(&stat[192 + c], r3[0]);
    }
}

// ---------------------------------------------------------------------------
// K2d: BN finalize from accumulated stats. 1 block x 64 thr.
// ---------------------------------------------------------------------------
__global__ __launch_bounds__(64) void k2d_bn(const float* __restrict__ stat,
                                             const float* __restrict__ g3,
                                             const float* __restrict__ b3,
                                             const float* __restrict__ g5,
                                             const float* __restrict__ b5,
                                             float* __restrict__ bnp) {
    const int c = threadIdx.x;
    const float inv_n = 1.0f / 65536.0f;
    float m1 = stat[c] * inv_n;
    float v1 = stat[64 + c] * inv_n - m1 * m1;
    float sc1 = g3[c] * rsqrtf(v1 + 1e-5f);
    float m2 = stat[128 + c] * inv_n;
    float v2 = stat[192 + c] * inv_n - m2 * m2;
    float sc2 = g5[c] * rsqrtf(v2 + 1e-5f);
    bnp[c] = sc1;
    bnp[64 + c] = b3[c] - m1 * sc1;
    bnp[128 + c] = sc2;
    bnp[192 + c] = b5[c] - m2 * sc2;
}

// ---------------------------------------------------------------------------
// K4: s = relu(bn(a1)) + relu(bn(a2)) + x3; attn = cw@s + cb; h5 += attn.
// 512 blocks x 256 thr; 128 positions x 64 ch per block.
// ---------------------------------------------------------------------------
__global__ __launch_bounds__(256) void k4_pointwise(float* __restrict__ h5,
                                                    const float* __restrict__ a1,
                                                    const float* __restrict__ a2,
                                                    const __hip_bfloat16* __restrict__ x3,
                                                    const float* __restrict__ cw,
                                                    const float* __restrict__ cb,
                                                    const float* __restrict__ bnp) {
    __shared__ float ls[64 * 129];
    __shared__ float cs[64 * 64];
    __shared__ float cbs[64];
    __shared__ float bns[256];
    const int tid = threadIdx.x;
    const int pos0 = blockIdx.x * 128;
    const int b = pos0 >> 15;
    const int rem = pos0 & 32767;
    const int t = rem >> 10;
    const int l0 = rem & 1023;
    const int pbase = b * 2097152 + t * 1024 + l0;

#pragma unroll
    for (int i = 0; i < 16; i++) cs[tid + i * 256] = cw[tid + i * 256];
    if (tid < 64) cbs[tid] = cb[tid];
    bns[tid] = bnp[tid];
    __syncthreads();

#pragma unroll
    for (int i = 0; i < 32; i++) {
        int q = tid + i * 256;
        int c = q >> 7, l = q & 127;
        int idx = pbase + c * 32768 + l;
        float v1 = fmaxf(bns[c] * a1[idx] + bns[64 + c], 0.f);
        float v2 = fmaxf(bns[128 + c] * a2[idx] + bns[192 + c], 0.f);
        ls[c * 129 + l] = v1 + v2 + __bfloat162float(x3[idx]);
    }
    __syncthreads();

    const int lidx = tid & 127;
    const int og = tid >> 7;
    float sreg[64];
#pragma unroll
    for (int c = 0; c < 64; c++) sreg[c] = ls[c * 129 + lidx];
    float acc[32];
#pragma unroll
    for (int oi = 0; oi < 32; oi++) acc[oi] = cbs[og * 32 + oi];
#pragma unroll
    for (int cq = 0; cq < 16; cq++) {
        float s0 = sreg[cq * 4], s1 = sreg[cq * 4 + 1];
        float s2 = sreg[cq * 4 + 2], s3 = sreg[cq * 4 + 3];
#pragma unroll
        for (int oi = 0; oi < 32; oi++) {
            float4 wv = *(const float4*)(cs + (og * 32 + oi) * 64 + cq * 4);
            acc[oi] += wv.x * s0 + wv.y * s1 + wv.z * s2 + wv.w * s3;
        }
    }
#pragma unroll
    for (int oi = 0; oi < 32; oi++) {
        int o = og * 32 + oi;
        int idx = pbase + o * 32768 + lidx;
        h5[idx] = h5[idx] + acc[oi];
    }
}

// ---------------------------------------------------------------------------
// K5: up GEMM + bias + GELU + residual -> FLOAT32 out.
// grid (3, 1024) x 256 thr; 64 rows x 128 cols per block; 8 rows x 4 cols
// per thread.
// ---------------------------------------------------------------------------
__global__ __launch_bounds__(256) void k5_up(const float* __restrict__ y5,
                                             const float* __restrict__ uw,
                                             const float* __restrict__ ub,
                                             const float* __restrict__ x,
                                             float* __restrict__ out) {
    __shared__ float ys_t[64 * 68];   // [row][k]
    __shared__ float wts[128 * 68];   // [c][k]
    const int tid = threadIdx.x;
    const int row0 = blockIdx.y * 64;
    const int c0 = blockIdx.x * 128;
    const int b = row0 >> 15;
    const int t = (row0 >> 10) & 31;
    const int l0 = row0 & 1023;
    const int ybase = b * 2097152 + t * 1024 + l0;

    // stage ys_t: 64 k x 64 r, global coalesced along r, LDS write stride 68
#pragma unroll
    for (int i = 0; i < 16; i++) {
        int e = tid + i * 256;
        int k = e >> 6, r = e & 63;
        ys_t[r * 68 + k] = y5[ybase + k * 32768 + r];
    }
    // stage wts: 128 c x 64 k, float4 both sides
#pragma unroll
    for (int i = 0; i < 8; i++) {
        int e = tid + i * 256;
        int c = e >> 4, k4 = e & 15;
        float4 v = *(const float4*)(uw + (c0 + c) * 64 + k4 * 4);
        *(float4*)(wts + c * 68 + k4 * 4) = v;
    }
    __syncthreads();

    const int cg = tid & 31;   // col lane: c = c0 + cg + 32*ci
    const int rg = tid >> 5;   // 0..7:     row = row0 + rg + 8*j
    float acc[8][4];
#pragma unroll
    for (int j = 0; j < 8; j++)
#pragma unroll
        for (int ci = 0; ci < 4; ci++) acc[j][ci] = 0.f;

#pragma unroll 2
    for (int kq = 0; kq < 16; kq++) {
        const int ko = kq * 4;
        float4 w0 = *(const float4*)(wts + (cg)      * 68 + ko);
        float4 w1 = *(const float4*)(wts + (cg + 32) * 68 + ko);
        float4 w2 = *(const float4*)(wts + (cg + 64) * 68 + ko);
        float4 w3 = *(const float4*)(wts + (cg + 96) * 68 + ko);
#pragma unroll
        for (int j = 0; j < 8; j++) {
            float4 yv = *(const float4*)(ys_t + (rg + 8 * j) * 68 + ko);
            acc[j][0] += yv.x * w0.x + yv.y * w0.y + yv.z * w0.z + yv.w * w0.w;
            acc[j][1] += yv.x * w1.x + yv.y * w1.y + yv.z * w1.z + yv.w * w1.w;
            acc[j][2] += yv.x * w2.x + yv.y * w2.y + yv.z * w2.z + yv.w * w2.w;
            acc[j][3] += yv.x * w3.x + yv.y * w3.y + yv.z * w3.z + yv.w * w3.w;
        }
    }

#pragma unroll
    for (int ci = 0; ci < 4; ci++) {
        int c = c0 + cg + 32 * ci;
        float ubv = ub[c];
#pragma unroll
        for (int j = 0; j < 8; j++) {
            int row = row0 + rg + 8 * j;
            float v = gelu_f(acc[j][ci] + ubv);
            out[row * 384 + c] = x[row * 384 + c] + v;
        }
    }
}

// ---------------------------------------------------------------------------
extern "C" void kernel_launch(void* const* d_in, const int* in_sizes, int n_in,
                              void* d_out, int out_size, void* d_ws, size_t ws_size,
                              hipStream_t stream) {
    const float* x      = (const float*)d_in[0];
    const float* down_w = (const float*)d_in[1];
    const float* down_b = (const float*)d_in[2];
    const float* k31w   = (const float*)d_in[3];
    const float* k31b   = (const float*)d_in[4];
    const float* k32w   = (const float*)d_in[5];
    const float* k32b   = (const float*)d_in[6];
    const float* bn3g   = (const float*)d_in[7];
    const float* bn3b   = (const float*)d_in[8];
    const float* k51w   = (const float*)d_in[9];
    const float* k51b   = (const float*)d_in[10];
    const float* k52w   = (const float*)d_in[11];
    const float* k52b   = (const float*)d_in[12];
    const float* bn5g   = (const float*)d_in[13];
    const float* bn5b   = (const float*)d_in[14];
    const float* conv_w = (const float*)d_in[15];
    const float* conv_b = (const float*)d_in[16];
    const float* fw     = (const float*)d_in[17];
    const float* fb     = (const float*)d_in[18];
    const float* up_w   = (const float*)d_in[19];
    const float* up_b   = (const float*)d_in[20];
    float* out = (float*)d_out;

    float* wsf = (float*)d_ws;
    float* gfb  = wsf + OFF_GF;
    float* bnp  = wsf + OFF_BN;
    float* stat = wsf + OFF_ST;
    float* h5   = wsf + OFF_H5;
    float* a1   = wsf + OFF_A1;
    float* a2   = wsf + OFF_A2;
    __hip_bfloat16* x3 = (__hip_bfloat16*)(wsf + OFF_X3);

    k0_prep<<<1, 64, 0, stream>>>(fw, fb, gfb, stat);
    k1_down<<<1024, 256, 0, stream>>>(x, down_w, down_b, h5);
    k2a_spatial<<<4096, 256, 0, stream>>>(h5, k31w, k31b, k51w, k51b, a1, a2);
    k2b_fft<<<512, 256, 0, stream>>>(h5, x3, gfb);
    k2c_temporal<<<512, 256, 0, stream>>>(a1, a2, k32w, k32b, k52w, k52b, stat);
    k2d_bn<<<1, 64, 0, stream>>>(stat, bn3g, bn3b, bn5g, bn5b, bnp);
    k4_pointwise<<<512, 256, 0, stream>>>(h5, a1, a2, x3, conv_w, conv_b, bnp);
    k5_up<<<dim3(3, 1024), 256, 0, stream>>>(h5, up_w, up_b, x, out);
}